// Round 9
// baseline (25717.218 us; speedup 1.0000x reference)
//
#include <hip/hip_runtime.h>
#include <hip/hip_bf16.h>
#include <math.h>

// Problem constants
#define B_ 64
#define S_ 64
#define E_ 256
#define H_ 512
#define V_ 50000
#define T_ 32
#define SOS_ 1
#define NCHUNK 196            // ceil(50000/256)
#define MARGIN 0.25f          // >= 2x worst-case bf16-dot error bound (~0.07)
static const long long LDCV = (long long)T_ * V_;   // out stride per batch row

typedef unsigned short u16;
typedef unsigned long long u64;
typedef u16   u16x8  __attribute__((ext_vector_type(8)));
typedef short bf16x8 __attribute__((ext_vector_type(8)));
typedef float f32x4  __attribute__((ext_vector_type(4)));

static __device__ __forceinline__ u16 f2bf(float f) {
    unsigned u = __float_as_uint(f);
    unsigned r = (u + 0x7FFFu + ((u >> 16) & 1u)) >> 16;
    return (u16)r;
}
static __device__ __forceinline__ unsigned pk2(float a, float b) {
    __hip_bfloat162 t = __float22bfloat162_rn(make_float2(a, b));
    unsigned r; __builtin_memcpy(&r, &t, 4); return r;
}
// monotonic float -> u32 (order-preserving for all finite values)
static __device__ __forceinline__ unsigned fenc(float f) {
    unsigned u = __float_as_uint(f);
    return u ^ ((u & 0x80000000u) ? 0xFFFFFFFFu : 0x80000000u);
}

// ---------------------------------------------------------------------------
// Setup (grid-stride to avoid dispatch storms)
// ---------------------------------------------------------------------------
__global__ __launch_bounds__(256) void build_wbig(
    const float* __restrict__ w_ih, const float* __restrict__ w_hh,
    const float* __restrict__ b_ih, const float* __restrict__ b_hh,
    float* __restrict__ WbigT, float* __restrict__ biasBig)
{
    for (int g = blockIdx.x * 256 + threadIdx.x; g < 2048 * 768;
         g += gridDim.x * 256) {
        int n = g / 768, k = g % 768;
        int j = n >> 2, c = n & 3;
        float v = 0.f;
        if (c == 0)      v = (k < 256) ? w_ih[j * 256 + k]          : w_hh[j * 512 + (k - 256)];
        else if (c == 1) v = (k < 256) ? w_ih[(512 + j) * 256 + k]  : w_hh[(512 + j) * 512 + (k - 256)];
        else if (c == 2) v = (k < 256) ? w_ih[(1024 + j) * 256 + k] : 0.f;
        else             v = (k < 256) ? 0.f                        : w_hh[(1024 + j) * 512 + (k - 256)];
        WbigT[g] = v;
    }
    int g0 = blockIdx.x * 256 + threadIdx.x;
    if (g0 < 2048) {
        int j = g0 >> 2, c = g0 & 3;
        float bv;
        if (c == 0)      bv = b_ih[j] + b_hh[j];
        else if (c == 1) bv = b_ih[512 + j] + b_hh[512 + j];
        else if (c == 2) bv = b_ih[1024 + j];
        else             bv = b_hh[1024 + j];
        biasBig[g0] = bv;
    }
}

__global__ __launch_bounds__(256) void transpose_aw(
    const float* __restrict__ attn_w, float* __restrict__ awT)
{
    int idx = blockIdx.x * 256 + threadIdx.x;
    int h = idx >> 9, g = idx & 511;
    awT[idx] = attn_w[g * 512 + h];
}

// h0 <- encoder_hidden[0]; tok <- SOS
__global__ __launch_bounds__(256) void init_state(
    const float* __restrict__ enc_hidden, float* __restrict__ hbuf0,
    int* __restrict__ tok)
{
    int idx = blockIdx.x * 256 + threadIdx.x;
    if (idx < B_ * H_) hbuf0[idx] = enc_hidden[idx];
    if (idx < B_) tok[idx] = SOS_;
}

// fc_w fp32 -> bf16 (one-time; RNE, identical to on-the-fly pk2 rounding)
__global__ __launch_bounds__(256) void conv_fcw(
    const float* __restrict__ fc_w, u16* __restrict__ fcwb)
{
    const size_t total = (size_t)V_ * 512;
    const size_t stride = (size_t)gridDim.x * 256 * 8;
    for (size_t i = ((size_t)blockIdx.x * 256 + threadIdx.x) * 8; i < total;
         i += stride) {
        float4 a = *(const float4*)&fc_w[i];
        float4 b = *(const float4*)&fc_w[i + 4];
        u16x8 o;
        o[0] = f2bf(a.x); o[1] = f2bf(a.y); o[2] = f2bf(a.z); o[3] = f2bf(a.w);
        o[4] = f2bf(b.x); o[5] = f2bf(b.y); o[6] = f2bf(b.z); o[7] = f2bf(b.w);
        *(u16x8*)&fcwb[i] = o;
    }
}

// ---------------------------------------------------------------------------
// gruh: gates GEMM (interleaved cols 4j+c) + GRU elementwise, fused.
// 64 blocks x 256 thr; tile 64m x 32n; micro 2x4 (keeps 4 gate cols/thread).
// ---------------------------------------------------------------------------
__global__ __launch_bounds__(256) void gruh(
    const float* __restrict__ WbigT, const float* __restrict__ biasBig,
    const float* __restrict__ emb, const int* __restrict__ tok,
    const float* __restrict__ hcur, float* __restrict__ hnxt,
    float* __restrict__ concatA)
{
    __shared__ float As[64][68];   // [kk][m]
    __shared__ float Ws[64][36];   // [kk][n], n in tile (32)
    const int tid = threadIdx.x;
    const int n0 = blockIdx.x * 32;
    const int tm = tid & 31;       // rows 2tm, 2tm+1
    const int tn = tid >> 5;       // cols 4tn .. 4tn+3 (8 groups)
    float acc[2][4] = {{0.f}};
    int tokm[4];
    #pragma unroll
    for (int r = 0; r < 4; ++r) tokm[r] = tok[(tid + r * 256) >> 4];

    for (int k0 = 0; k0 < 768; k0 += 64) {
        #pragma unroll
        for (int r = 0; r < 4; ++r) {
            int idx = tid + r * 256;
            int m = idx >> 4;
            int kk = (idx & 15) << 2;
            int k = k0 + kk;
            float4 v = (k < 256)
                ? *(const float4*)&emb[(size_t)tokm[r] * 256 + k]
                : *(const float4*)&hcur[m * 512 + (k - 256)];
            As[kk + 0][m] = v.x; As[kk + 1][m] = v.y;
            As[kk + 2][m] = v.z; As[kk + 3][m] = v.w;
        }
        #pragma unroll
        for (int r = 0; r < 2; ++r) {
            int idx = tid + r * 256;
            int n = idx >> 4;                   // 0..31
            int kk = (idx & 15) << 2;
            float4 v = *(const float4*)&WbigT[(size_t)(n0 + n) * 768 + k0 + kk];
            Ws[kk + 0][n] = v.x; Ws[kk + 1][n] = v.y;
            Ws[kk + 2][n] = v.z; Ws[kk + 3][n] = v.w;
        }
        __syncthreads();
        #pragma unroll
        for (int kk = 0; kk < 64; ++kk) {
            float2 a = *(const float2*)&As[kk][tm << 1];
            float4 w = *(const float4*)&Ws[kk][tn << 2];
            acc[0][0] += a.x * w.x; acc[0][1] += a.x * w.y;
            acc[0][2] += a.x * w.z; acc[0][3] += a.x * w.w;
            acc[1][0] += a.y * w.x; acc[1][1] += a.y * w.y;
            acc[1][2] += a.y * w.z; acc[1][3] += a.y * w.w;
        }
        __syncthreads();
    }

    int jg = (n0 >> 2) + tn;       // this thread's hidden unit j
    float b0 = biasBig[(jg << 2) + 0], b1 = biasBig[(jg << 2) + 1];
    float b2 = biasBig[(jg << 2) + 2], b3 = biasBig[(jg << 2) + 3];
    #pragma unroll
    for (int i = 0; i < 2; ++i) {
        int m = (tm << 1) + i;
        float g0 = acc[i][0] + b0, g1 = acc[i][1] + b1;
        float g2 = acc[i][2] + b2, g3 = acc[i][3] + b3;
        float r_ = 1.f / (1.f + expf(-g0));
        float z_ = 1.f / (1.f + expf(-g1));
        float nn = tanhf(g2 + r_ * g3);
        float hv = hcur[m * 512 + jg];
        float h2 = (1.f - z_) * nn + z_ * hv;
        hnxt[m * 512 + jg] = h2;
        concatA[m * 1024 + jg] = h2;
    }
}

// ---------------------------------------------------------------------------
// attnq: q = h_new @ attn_w, scores, softmax, context. One block per b.
// ---------------------------------------------------------------------------
__global__ __launch_bounds__(256) void attnq(
    const float* __restrict__ hnew, const float* __restrict__ awT,
    const float* __restrict__ enc, float* __restrict__ concatA)
{
    int b = blockIdx.x, tid = threadIdx.x;
    __shared__ float hs[512], q[512], aw[64];
    hs[tid] = hnew[b * 512 + tid];
    hs[tid + 256] = hnew[b * 512 + 256 + tid];
    __syncthreads();
    #pragma unroll
    for (int hh = 0; hh < 2; ++hh) {
        int h = tid + hh * 256;
        const float4* wr = (const float4*)(awT + (size_t)h * 512);
        float a = 0.f;
        #pragma unroll 8
        for (int k = 0; k < 128; ++k) {
            float4 w4 = wr[k];
            a += hs[4 * k] * w4.x + hs[4 * k + 1] * w4.y
               + hs[4 * k + 2] * w4.z + hs[4 * k + 3] * w4.w;
        }
        q[h] = a;
    }
    __syncthreads();
    int wv = tid >> 6, ln = tid & 63;
    for (int si = 0; si < 16; ++si) {
        int s = wv * 16 + si;
        const float* er = enc + ((size_t)(b * 64 + s)) * 512;
        float p = 0.f;
        #pragma unroll
        for (int i = 0; i < 8; ++i) p += q[ln + (i << 6)] * er[ln + (i << 6)];
        for (int off = 32; off; off >>= 1) p += __shfl_down(p, off);
        if (ln == 0) aw[s] = p;
    }
    __syncthreads();
    if (tid < 64) {
        float v = aw[tid], m = v;
        for (int off = 32; off; off >>= 1) m = fmaxf(m, __shfl_xor(m, off));
        float e = __expf(v - m);
        float ssum = e;
        for (int off = 32; off; off >>= 1) ssum += __shfl_xor(ssum, off);
        aw[tid] = e / ssum;
    }
    __syncthreads();
    #pragma unroll
    for (int hh = 0; hh < 2; ++hh) {
        int h = tid + hh * 256;
        float c = 0.f;
        const float* eb = enc + (size_t)b * 64 * 512 + h;
        #pragma unroll 8
        for (int s = 0; s < 64; ++s) c += aw[s] * eb[s * 512];
        concatA[b * 1024 + 512 + h] = c;
    }
}

// ---------------------------------------------------------------------------
// ctxtanh: [h|ctx] @ Wa^T, tanh, write fp32 + bf16. 32 blocks; tile 64m x 16n.
// ---------------------------------------------------------------------------
__global__ __launch_bounds__(256) void ctxtanh(
    const float* __restrict__ concatA, const float* __restrict__ Wa,
    float* __restrict__ Abuf, u16* __restrict__ Abufb)
{
    __shared__ float As[64][68];   // [kk][m]
    __shared__ float Ws[64][20];   // [kk][n], n in tile (16)
    const int tid = threadIdx.x;
    const int n0 = blockIdx.x * 16;
    const int tm = tid & 63;       // row
    const int tn = tid >> 6;       // cols 4tn..4tn+3 (4 groups)
    float acc[4] = {0.f, 0.f, 0.f, 0.f};

    for (int k0 = 0; k0 < 1024; k0 += 64) {
        #pragma unroll
        for (int r = 0; r < 4; ++r) {
            int idx = tid + r * 256;
            int m = idx >> 4;
            int kk = (idx & 15) << 2;
            float4 v = *(const float4*)&concatA[(size_t)m * 1024 + k0 + kk];
            As[kk + 0][m] = v.x; As[kk + 1][m] = v.y;
            As[kk + 2][m] = v.z; As[kk + 3][m] = v.w;
        }
        {
            int n = tid >> 4;                  // 0..15
            int kk = (tid & 15) << 2;
            float4 v = *(const float4*)&Wa[(size_t)(n0 + n) * 1024 + k0 + kk];
            Ws[kk + 0][n] = v.x; Ws[kk + 1][n] = v.y;
            Ws[kk + 2][n] = v.z; Ws[kk + 3][n] = v.w;
        }
        __syncthreads();
        #pragma unroll
        for (int kk = 0; kk < 64; ++kk) {
            float a = As[kk][tm];
            float4 w = *(const float4*)&Ws[kk][tn << 2];
            acc[0] += a * w.x; acc[1] += a * w.y;
            acc[2] += a * w.z; acc[3] += a * w.w;
        }
        __syncthreads();
    }
    #pragma unroll
    for (int j2 = 0; j2 < 4; ++j2) {
        int n = n0 + (tn << 2) + j2;
        float th = tanhf(acc[j2]);
        Abuf[tm * 512 + n] = th;
        Abufb[tm * 512 + n] = f2bf(th);
    }
}

// ---------------------------------------------------------------------------
// Logits GEMM via bf16 MFMA. CACHED=1: B from pre-converted bf16 cache;
// CACHED=0: fc_w fp32 converted on the fly (identical RNE rounding).
// Writes raw biased logits + per-chunk (max, sumexp) partials.
// ---------------------------------------------------------------------------
template <int CACHED>
__global__ __launch_bounds__(256) void logits_mfma(
    const u16* __restrict__ Abufb, const float* __restrict__ fcw,
    const u16* __restrict__ fcwb, const float* __restrict__ fc_b,
    float* __restrict__ outp, float* __restrict__ pmax,
    float* __restrict__ psum)
{
    __shared__ u16 sA[64 * 512];     // 64KB, XOR-swizzled; reused after
    const int tid = threadIdx.x;
    const int wv = tid >> 6, lane = tid & 63;
    const int nb = blockIdx.x * 256;
    const int col16 = lane & 15, grp = lane >> 4;

    #pragma unroll
    for (int i = 0; i < 16; ++i) {
        int c = tid + i * 256;
        int m = c >> 6;
        int cb = (c & 63) << 4;
        int sb = cb ^ ((m & 7) << 4);
        *(u16x8*)((char*)sA + m * 1024 + sb) =
            *(const u16x8*)(Abufb + m * 512 + (cb >> 1));
    }
    __syncthreads();

    int nfb[4]; bool val[4];
    #pragma unroll
    for (int fn = 0; fn < 4; ++fn) {
        nfb[fn] = nb + wv * 64 + fn * 16;
        val[fn] = nfb[fn] < V_;
    }

    f32x4 acc[4][4];
    #pragma unroll
    for (int a = 0; a < 4; ++a)
        #pragma unroll
        for (int b2 = 0; b2 < 4; ++b2) acc[a][b2] = (f32x4){0.f, 0.f, 0.f, 0.f};

    if (CACHED) {
        const u16* wpb[4];
        #pragma unroll
        for (int fn = 0; fn < 4; ++fn) {
            size_t rowi = val[fn] ? (size_t)(nfb[fn] + col16) : 0;
            wpb[fn] = fcwb + rowi * 512 + (grp << 3);
        }
        bf16x8 bcur[4];
        #pragma unroll
        for (int fn = 0; fn < 4; ++fn) bcur[fn] = *(const bf16x8*)(wpb[fn]);
        for (int kt = 0; kt < 16; ++kt) {
            bf16x8 bnxt[4];
            int ktn = (kt < 15) ? kt + 1 : 15;
            #pragma unroll
            for (int fn = 0; fn < 4; ++fn)
                bnxt[fn] = *(const bf16x8*)(wpb[fn] + ktn * 32);
            bf16x8 af[4];
            int kb = kt * 64 + (grp << 4);
            #pragma unroll
            for (int fm = 0; fm < 4; ++fm) {
                int mg = fm * 16 + col16;
                af[fm] = *(const bf16x8*)((const char*)sA + mg * 1024 + (kb ^ ((mg & 7) << 4)));
            }
            #pragma unroll
            for (int fm = 0; fm < 4; ++fm)
                #pragma unroll
                for (int fn = 0; fn < 4; ++fn)
                    acc[fm][fn] = __builtin_amdgcn_mfma_f32_16x16x32_bf16(
                        af[fm], bcur[fn], acc[fm][fn], 0, 0, 0);
            #pragma unroll
            for (int fn = 0; fn < 4; ++fn) bcur[fn] = bnxt[fn];
        }
    } else {
        const float* wp[4];
        #pragma unroll
        for (int fn = 0; fn < 4; ++fn) {
            size_t rowi = val[fn] ? (size_t)(nfb[fn] + col16) : 0;
            wp[fn] = fcw + rowi * 512 + (grp << 3);
        }
        float4 lo[4], hi[4];
        #pragma unroll
        for (int fn = 0; fn < 4; ++fn) {
            lo[fn] = *(const float4*)(wp[fn]);
            hi[fn] = *(const float4*)(wp[fn] + 4);
        }
        for (int kt = 0; kt < 16; ++kt) {
            float4 nl[4], nh[4];
            int ktn = (kt < 15) ? kt + 1 : 15;
            #pragma unroll
            for (int fn = 0; fn < 4; ++fn) {
                nl[fn] = *(const float4*)(wp[fn] + ktn * 32);
                nh[fn] = *(const float4*)(wp[fn] + ktn * 32 + 4);
            }
            bf16x8 bc[4];
            #pragma unroll
            for (int fn = 0; fn < 4; ++fn) {
                union { unsigned u[4]; bf16x8 v; } cv;
                cv.u[0] = pk2(lo[fn].x, lo[fn].y);
                cv.u[1] = pk2(lo[fn].z, lo[fn].w);
                cv.u[2] = pk2(hi[fn].x, hi[fn].y);
                cv.u[3] = pk2(hi[fn].z, hi[fn].w);
                bc[fn] = cv.v;
            }
            bf16x8 af[4];
            int kb = kt * 64 + (grp << 4);
            #pragma unroll
            for (int fm = 0; fm < 4; ++fm) {
                int mg = fm * 16 + col16;
                af[fm] = *(const bf16x8*)((const char*)sA + mg * 1024 + (kb ^ ((mg & 7) << 4)));
            }
            #pragma unroll
            for (int fm = 0; fm < 4; ++fm)
                #pragma unroll
                for (int fn = 0; fn < 4; ++fn)
                    acc[fm][fn] = __builtin_amdgcn_mfma_f32_16x16x32_bf16(
                        af[fm], bc[fn], acc[fm][fn], 0, 0, 0);
            #pragma unroll
            for (int fn = 0; fn < 4; ++fn) { lo[fn] = nl[fn]; hi[fn] = nh[fn]; }
        }
    }
    __syncthreads();   // A reads done; reuse sA

    float* wmaxp = (float*)sA;            // [4][64]
    float* wsump = (float*)(sA + 512);

    float bias[4];
    #pragma unroll
    for (int fn = 0; fn < 4; ++fn) bias[fn] = val[fn] ? fc_b[nfb[fn] + col16] : 0.f;

    #pragma unroll
    for (int fm = 0; fm < 4; ++fm) {
        #pragma unroll
        for (int r = 0; r < 4; ++r) {
            int mrow = fm * 16 + grp * 4 + r;
            float best = -INFINITY;
            float vv[4];
            #pragma unroll
            for (int fn = 0; fn < 4; ++fn) {
                float v = -INFINITY;
                if (val[fn]) {
                    v = acc[fm][fn][r] + bias[fn];
                    outp[(size_t)mrow * LDCV + nfb[fn] + col16] = v;
                    best = fmaxf(best, v);
                }
                vv[fn] = v;
            }
            #pragma unroll
            for (int d = 1; d < 16; d <<= 1) best = fmaxf(best, __shfl_xor(best, d));
            float s = 0.f;
            #pragma unroll
            for (int fn = 0; fn < 4; ++fn)
                if (val[fn]) s += __expf(vv[fn] - best);
            #pragma unroll
            for (int d = 1; d < 16; d <<= 1) s += __shfl_xor(s, d);
            if (col16 == 0) {
                wmaxp[wv * 64 + mrow] = best;
                wsump[wv * 64 + mrow] = s;
            }
        }
    }
    __syncthreads();
    if (tid < 64) {
        float gm = -INFINITY;
        #pragma unroll
        for (int w = 0; w < 4; ++w) gm = fmaxf(gm, wmaxp[w * 64 + tid]);
        float gs = 0.f;
        #pragma unroll
        for (int w = 0; w < 4; ++w)
            gs += wsump[w * 64 + tid] * __expf(wmaxp[w * 64 + tid] - gm);
        pmax[tid * NCHUNK + blockIdx.x] = gm;
        psum[tid * NCHUNK + blockIdx.x] = gs;
    }
}

// ---------------------------------------------------------------------------
// refine64: one block per batch row b (64 blocks, atomic-free).
// Row max + logZ from chunk partials; global-max-gated chunks, per-column
// gate, exact fp32 recompute; block-reduce (value,idx) -> tok[b].
// ---------------------------------------------------------------------------
__global__ __launch_bounds__(256) void refine64(
    const float* __restrict__ pmax, const float* __restrict__ psum,
    const float* __restrict__ outp /* out + t*V_ */,
    const float* __restrict__ Abuf, const float* __restrict__ fcw,
    const float* __restrict__ fc_b, float* __restrict__ logZ_arr,
    int* __restrict__ tok, int t)
{
    __shared__ float sv[256];
    __shared__ float A[512];
    __shared__ u64 sp[256];
    __shared__ int clist[200];
    __shared__ int ccnt;
    const int b = blockIdx.x, tid = threadIdx.x;
    const float* pm = pmax + (size_t)b * NCHUNK;
    const float* ps = psum + (size_t)b * NCHUNK;

    float pmv = (tid < NCHUNK) ? pm[tid] : -INFINITY;
    sv[tid] = pmv; __syncthreads();
    for (int st = 128; st; st >>= 1) {
        if (tid < st) sv[tid] = fmaxf(sv[tid], sv[tid + st]);
        __syncthreads();
    }
    float Mb = sv[0]; __syncthreads();

    sv[tid] = (tid < NCHUNK) ? ps[tid] * __expf(pmv - Mb) : 0.f;
    __syncthreads();
    for (int st = 128; st; st >>= 1) {
        if (tid < st) sv[tid] += sv[tid + st];
        __syncthreads();
    }
    if (tid == 0) { logZ_arr[b * T_ + t] = Mb + logf(sv[0]); ccnt = 0; }
    A[tid] = Abuf[b * 512 + tid];
    A[tid + 256] = Abuf[b * 512 + 256 + tid];
    __syncthreads();

    if (tid < NCHUNK && pmv >= Mb - MARGIN) {
        int s = atomicAdd(&ccnt, 1);       // LDS atomic; order-independent result
        clist[s] = tid;
    }
    __syncthreads();
    int nc = ccnt;

    u64 best = 0ull;
    for (int ci = 0; ci < nc; ++ci) {
        int n = clist[ci] * 256 + tid;
        if (n < V_) {
            float L = outp[(size_t)b * LDCV + n];
            if (L >= Mb - MARGIN) {
                const float* wr = fcw + (size_t)n * 512;
                float d = fc_b[n];
                #pragma unroll 8
                for (int k = 0; k < 512; k += 4) {
                    float4 w4 = *(const float4*)&wr[k];
                    d += A[k] * w4.x + A[k + 1] * w4.y
                       + A[k + 2] * w4.z + A[k + 3] * w4.w;
                }
                u64 pk = ((u64)fenc(d) << 32) | (u64)(~(unsigned)n);
                if (pk > best) best = pk;
            }
        }
    }
    sp[tid] = best; __syncthreads();
    for (int st = 128; st; st >>= 1) {
        if (tid < st) { u64 o = sp[tid + st]; if (o > sp[tid]) sp[tid] = o; }
        __syncthreads();
    }
    if (tid == 0) tok[b] = (int)(~(unsigned)(sp[0] & 0xFFFFFFFFull));
}

// out[row][:] -= logZ[row]; one block per row (2048 blocks), grid-stride cols.
__global__ __launch_bounds__(256) void norm_all(
    float* __restrict__ out, const float* __restrict__ logZ_arr)
{
    int row = blockIdx.x;
    float z = logZ_arr[row];
    float4* base = (float4*)(out + (size_t)row * V_);
    for (int j = threadIdx.x; j < 12500; j += 256) {
        float4 v = base[j];
        v.x -= z; v.y -= z; v.z -= z; v.w -= z;
        base[j] = v;
    }
}

__global__ __launch_bounds__(256) void final_copy(
    const float* __restrict__ hfin, float* __restrict__ dst)
{
    int idx = blockIdx.x * 256 + threadIdx.x;
    if (idx < B_ * H_) dst[idx] = hfin[idx];
}

// ---------------------------------------------------------------------------
extern "C" void kernel_launch(void* const* d_in, const int* in_sizes, int n_in,
                              void* d_out, int out_size, void* d_ws, size_t ws_size,
                              hipStream_t stream)
{
    const float* enc_hidden = (const float*)d_in[0];
    const float* enc    = (const float*)d_in[3];
    const float* emb    = (const float*)d_in[4];
    const float* w_ih   = (const float*)d_in[5];
    const float* w_hh   = (const float*)d_in[6];
    const float* b_ih   = (const float*)d_in[7];
    const float* b_hh   = (const float*)d_in[8];
    const float* attn_w = (const float*)d_in[9];
    const float* Wa     = (const float*)d_in[10];
    const float* fc_w   = (const float*)d_in[11];
    const float* fc_b   = (const float*)d_in[12];
    float* out = (float*)d_out;
    float* ws  = (float*)d_ws;

    // ws layout (float units) — base ≈ 8.2 MB (+51.2 MB bf16 cache if it fits)
    size_t off = 0;
    float* WbigT   = ws + off; off += 1572864;
    float* biasBig = ws + off; off += 2048;
    float* awT     = ws + off; off += 262144;
    float* hbuf0   = ws + off; off += 32768;
    float* hbuf1   = ws + off; off += 32768;
    float* concatA = ws + off; off += 65536;
    float* Abuf    = ws + off; off += 32768;
    u16*   Abufb   = (u16*)(ws + off); off += 16384;
    float* pmax    = ws + off; off += 64 * NCHUNK;
    float* psum    = ws + off; off += 64 * NCHUNK;
    float* logZ_a  = ws + off; off += 64 * T_;
    int*   tok     = (int*)(ws + off); off += 64;
    off = (off + 3) & ~(size_t)3;                    // 16B-align the bf16 cache
    u16*   fcwb    = (u16*)(ws + off);
    const bool big = ws_size >= (off + 12800000) * 4;   // + 50000*512 bf16

    build_wbig<<<1536, 256, 0, stream>>>(w_ih, w_hh, b_ih, b_hh, WbigT, biasBig);
    transpose_aw<<<1024, 256, 0, stream>>>(attn_w, awT);
    init_state<<<128, 256, 0, stream>>>(enc_hidden, hbuf0, tok);
    if (big) conv_fcw<<<2048, 256, 0, stream>>>(fc_w, fcwb);

    for (int t = 0; t < T_; ++t) {
        float* hcur = (t & 1) ? hbuf1 : hbuf0;
        float* hnxt = (t & 1) ? hbuf0 : hbuf1;
        float* outp = out + (size_t)t * V_;

        gruh<<<64, 256, 0, stream>>>(WbigT, biasBig, emb, tok, hcur, hnxt, concatA);
        attnq<<<64, 256, 0, stream>>>(hnxt, awT, enc, concatA);
        ctxtanh<<<32, 256, 0, stream>>>(concatA, Wa, Abuf, Abufb);
        if (big)
            logits_mfma<1><<<NCHUNK, 256, 0, stream>>>(
                Abufb, fc_w, fcwb, fc_b, outp, pmax, psum);
        else
            logits_mfma<0><<<NCHUNK, 256, 0, stream>>>(
                Abufb, fc_w, fcwb, fc_b, outp, pmax, psum);
        refine64<<<64, 256, 0, stream>>>(
            pmax, psum, outp, Abuf, fc_w, fc_b, logZ_a, tok, t);
    }

    norm_all<<<2048, 256, 0, stream>>>(out, logZ_a);
    final_copy<<<128, 256, 0, stream>>>(hbuf0, out + (size_t)B_ * T_ * V_);
}

// Round 10
// 5166.059 us; speedup vs baseline: 4.9781x; 4.9781x over previous
//
#include <hip/hip_runtime.h>
#include <hip/hip_bf16.h>
#include <math.h>

// Problem constants
#define B_ 64
#define S_ 64
#define E_ 256
#define H_ 512
#define V_ 50000
#define T_ 32
#define SOS_ 1
#define NCHUNK 196            // ceil(50000/256)
#define MARGIN 0.25f          // >= 2x worst-case bf16-dot error bound (~0.07)
static const long long LDCV = (long long)T_ * V_;   // out stride per batch row

typedef unsigned short u16;
typedef unsigned long long u64;
typedef u16   u16x8  __attribute__((ext_vector_type(8)));
typedef short bf16x8 __attribute__((ext_vector_type(8)));
typedef float f32x4  __attribute__((ext_vector_type(4)));

static __device__ __forceinline__ u16 f2bf(float f) {
    unsigned u = __float_as_uint(f);
    unsigned r = (u + 0x7FFFu + ((u >> 16) & 1u)) >> 16;
    return (u16)r;
}
static __device__ __forceinline__ unsigned pk2(float a, float b) {
    __hip_bfloat162 t = __float22bfloat162_rn(make_float2(a, b));
    unsigned r; __builtin_memcpy(&r, &t, 4); return r;
}
// monotonic float <-> u32 (order-preserving for all finite values)
static __device__ __forceinline__ unsigned fenc(float f) {
    unsigned u = __float_as_uint(f);
    return u ^ ((u & 0x80000000u) ? 0xFFFFFFFFu : 0x80000000u);
}
static __device__ __forceinline__ float fdec(unsigned e) {
    unsigned u = (e & 0x80000000u) ? (e ^ 0x80000000u) : ~e;
    return __uint_as_float(u);
}

// ---------------------------------------------------------------------------
// Setup (grid-stride)
// ---------------------------------------------------------------------------
__global__ __launch_bounds__(256) void build_wbig(
    const float* __restrict__ w_ih, const float* __restrict__ w_hh,
    const float* __restrict__ b_ih, const float* __restrict__ b_hh,
    float* __restrict__ WbigT, float* __restrict__ biasBig)
{
    for (int g = blockIdx.x * 256 + threadIdx.x; g < 2048 * 768;
         g += gridDim.x * 256) {
        int n = g / 768, k = g % 768;
        int j = n >> 2, c = n & 3;
        float v = 0.f;
        if (c == 0)      v = (k < 256) ? w_ih[j * 256 + k]          : w_hh[j * 512 + (k - 256)];
        else if (c == 1) v = (k < 256) ? w_ih[(512 + j) * 256 + k]  : w_hh[(512 + j) * 512 + (k - 256)];
        else if (c == 2) v = (k < 256) ? w_ih[(1024 + j) * 256 + k] : 0.f;
        else             v = (k < 256) ? 0.f                        : w_hh[(1024 + j) * 512 + (k - 256)];
        WbigT[g] = v;
    }
    int g0 = blockIdx.x * 256 + threadIdx.x;
    if (g0 < 2048) {
        int j = g0 >> 2, c = g0 & 3;
        float bv;
        if (c == 0)      bv = b_ih[j] + b_hh[j];
        else if (c == 1) bv = b_ih[512 + j] + b_hh[512 + j];
        else if (c == 2) bv = b_ih[1024 + j];
        else             bv = b_hh[1024 + j];
        biasBig[g0] = bv;
    }
}

__global__ __launch_bounds__(256) void transpose_aw(
    const float* __restrict__ attn_w, float* __restrict__ awT)
{
    int idx = blockIdx.x * 256 + threadIdx.x;
    int h = idx >> 9, g = idx & 511;
    awT[idx] = attn_w[g * 512 + h];
}

// h0 <- encoder_hidden[0]; win64 <- packed SOS; rowmax <- 0
__global__ __launch_bounds__(256) void init_state(
    const float* __restrict__ enc_hidden, float* __restrict__ hbuf0,
    u64* __restrict__ win64, unsigned* __restrict__ rowmax)
{
    int idx = blockIdx.x * 256 + threadIdx.x;
    if (idx < B_ * H_) hbuf0[idx] = enc_hidden[idx];
    if (idx < B_) {
        win64[idx] = (u64)(~(unsigned)SOS_);   // low32 = ~SOS -> decodes to SOS
        rowmax[idx] = 0u;
    }
}

// fc_w fp32 -> bf16 (one-time; RNE, identical to on-the-fly pk2 rounding)
__global__ __launch_bounds__(256) void conv_fcw(
    const float* __restrict__ fc_w, u16* __restrict__ fcwb)
{
    const size_t total = (size_t)V_ * 512;
    const size_t stride = (size_t)gridDim.x * 256 * 8;
    for (size_t i = ((size_t)blockIdx.x * 256 + threadIdx.x) * 8; i < total;
         i += stride) {
        float4 a = *(const float4*)&fc_w[i];
        float4 b = *(const float4*)&fc_w[i + 4];
        u16x8 o;
        o[0] = f2bf(a.x); o[1] = f2bf(a.y); o[2] = f2bf(a.z); o[3] = f2bf(a.w);
        o[4] = f2bf(b.x); o[5] = f2bf(b.y); o[6] = f2bf(b.z); o[7] = f2bf(b.w);
        *(u16x8*)&fcwb[i] = o;
    }
}

// ---------------------------------------------------------------------------
// gruh: gates GEMM (interleaved cols 4j+c) + GRU elementwise, fused.
// 128 blocks (2 m-halves x 64 n-tiles); tile 32m x 32n; 1x4 micro.
// Per-output k-order ascending (bit-identical to the 64-block version).
// ---------------------------------------------------------------------------
__global__ __launch_bounds__(256) void gruh(
    const float* __restrict__ WbigT, const float* __restrict__ biasBig,
    const float* __restrict__ emb, const u64* __restrict__ win64,
    const float* __restrict__ hcur, float* __restrict__ hnxt,
    float* __restrict__ concatA)
{
    __shared__ float As[64][36];   // [kk][m], m in tile (32)
    __shared__ float Ws[64][36];   // [kk][n], n in tile (32)
    const int tid = threadIdx.x;
    const int nb = blockIdx.x & 63;   // n-tile: cols nb*32..+31
    const int mb = blockIdx.x >> 6;   // m-half: rows mb*32..+31
    const int n0 = nb * 32, m0 = mb * 32;
    const int tm = tid & 31;          // row within tile
    const int tn = tid >> 5;          // j-quad within tile (0..7)
    float acc[4] = {0.f, 0.f, 0.f, 0.f};
    int tokm[2];
    #pragma unroll
    for (int r = 0; r < 2; ++r) {
        int m = (tid + r * 256) >> 4;    // 0..31
        tokm[r] = (int)(~(unsigned)(win64[m0 + m] & 0xFFFFFFFFull));
    }

    for (int k0 = 0; k0 < 768; k0 += 64) {
        #pragma unroll
        for (int r = 0; r < 2; ++r) {
            int idx = tid + r * 256;
            int m = idx >> 4;            // 0..31
            int kk = (idx & 15) << 2;
            int k = k0 + kk;
            float4 v = (k < 256)
                ? *(const float4*)&emb[(size_t)tokm[r] * 256 + k]
                : *(const float4*)&hcur[(m0 + m) * 512 + (k - 256)];
            As[kk + 0][m] = v.x; As[kk + 1][m] = v.y;
            As[kk + 2][m] = v.z; As[kk + 3][m] = v.w;
        }
        #pragma unroll
        for (int r = 0; r < 2; ++r) {
            int idx = tid + r * 256;
            int n = idx >> 4;            // 0..31
            int kk = (idx & 15) << 2;
            float4 v = *(const float4*)&WbigT[(size_t)(n0 + n) * 768 + k0 + kk];
            Ws[kk + 0][n] = v.x; Ws[kk + 1][n] = v.y;
            Ws[kk + 2][n] = v.z; Ws[kk + 3][n] = v.w;
        }
        __syncthreads();
        #pragma unroll
        for (int kk = 0; kk < 64; ++kk) {
            float a = As[kk][tm];
            float4 w = *(const float4*)&Ws[kk][tn << 2];
            acc[0] += a * w.x; acc[1] += a * w.y;
            acc[2] += a * w.z; acc[3] += a * w.w;
        }
        __syncthreads();
    }

    int jg = (n0 >> 2) + tn;             // hidden unit j
    float b0 = biasBig[(jg << 2) + 0], b1 = biasBig[(jg << 2) + 1];
    float b2 = biasBig[(jg << 2) + 2], b3 = biasBig[(jg << 2) + 3];
    int m = m0 + tm;
    float g0 = acc[0] + b0, g1 = acc[1] + b1;
    float g2 = acc[2] + b2, g3 = acc[3] + b3;
    float r_ = 1.f / (1.f + expf(-g0));
    float z_ = 1.f / (1.f + expf(-g1));
    float nn = tanhf(g2 + r_ * g3);
    float hv = hcur[m * 512 + jg];
    float h2 = (1.f - z_) * nn + z_ * hv;
    hnxt[m * 512 + jg] = h2;
    concatA[m * 1024 + jg] = h2;
}

// ---------------------------------------------------------------------------
// attnq: q = h_new @ attn_w, scores, softmax, context. One block per b.
// ---------------------------------------------------------------------------
__global__ __launch_bounds__(256) void attnq(
    const float* __restrict__ hnew, const float* __restrict__ awT,
    const float* __restrict__ enc, float* __restrict__ concatA)
{
    int b = blockIdx.x, tid = threadIdx.x;
    __shared__ float hs[512], q[512], aw[64];
    hs[tid] = hnew[b * 512 + tid];
    hs[tid + 256] = hnew[b * 512 + 256 + tid];
    __syncthreads();
    #pragma unroll
    for (int hh = 0; hh < 2; ++hh) {
        int h = tid + hh * 256;
        const float4* wr = (const float4*)(awT + (size_t)h * 512);
        float a = 0.f;
        #pragma unroll 8
        for (int k = 0; k < 128; ++k) {
            float4 w4 = wr[k];
            a += hs[4 * k] * w4.x + hs[4 * k + 1] * w4.y
               + hs[4 * k + 2] * w4.z + hs[4 * k + 3] * w4.w;
        }
        q[h] = a;
    }
    __syncthreads();
    int wv = tid >> 6, ln = tid & 63;
    for (int si = 0; si < 16; ++si) {
        int s = wv * 16 + si;
        const float* er = enc + ((size_t)(b * 64 + s)) * 512;
        float p = 0.f;
        #pragma unroll
        for (int i = 0; i < 8; ++i) p += q[ln + (i << 6)] * er[ln + (i << 6)];
        for (int off = 32; off; off >>= 1) p += __shfl_down(p, off);
        if (ln == 0) aw[s] = p;
    }
    __syncthreads();
    if (tid < 64) {
        float v = aw[tid], m = v;
        for (int off = 32; off; off >>= 1) m = fmaxf(m, __shfl_xor(m, off));
        float e = __expf(v - m);
        float ssum = e;
        for (int off = 32; off; off >>= 1) ssum += __shfl_xor(ssum, off);
        aw[tid] = e / ssum;
    }
    __syncthreads();
    #pragma unroll
    for (int hh = 0; hh < 2; ++hh) {
        int h = tid + hh * 256;
        float c = 0.f;
        const float* eb = enc + (size_t)b * 64 * 512 + h;
        #pragma unroll 8
        for (int s = 0; s < 64; ++s) c += aw[s] * eb[s * 512];
        concatA[b * 1024 + 512 + h] = c;
    }
}

// ---------------------------------------------------------------------------
// ctxtanh: [h|ctx] @ Wa^T, tanh, write fp32 + bf16. 128 blocks
// (4 m-tiles x 32 n-tiles, 16x16); one output per thread, ascending-k.
// Block 0 also resets the per-row atomic cells for this step.
// ---------------------------------------------------------------------------
__global__ __launch_bounds__(256) void ctxtanh(
    const float* __restrict__ concatA, const float* __restrict__ Wa,
    float* __restrict__ Abuf, u16* __restrict__ Abufb,
    u64* __restrict__ win64, unsigned* __restrict__ rowmax)
{
    __shared__ float As[64][20];   // [kk][m], m in tile (16)
    __shared__ float Ws[64][20];   // [kk][n], n in tile (16)
    const int tid = threadIdx.x;
    const int nb = blockIdx.x & 31;   // cols nb*16..+15
    const int mb = blockIdx.x >> 5;   // rows mb*16..+15
    const int n0 = nb * 16, m0 = mb * 16;
    const int tm = tid & 15, tn = tid >> 4;   // row tm, col tn (0..15)
    if (blockIdx.x == 0 && tid < 64) {        // reset atomics for this step
        win64[tid] = 0ull;
        rowmax[tid] = 0u;
    }
    float acc = 0.f;

    for (int k0 = 0; k0 < 1024; k0 += 64) {
        {
            int m = tid >> 4;                 // 0..15
            int kk = (tid & 15) << 2;
            float4 v = *(const float4*)&concatA[(size_t)(m0 + m) * 1024 + k0 + kk];
            As[kk + 0][m] = v.x; As[kk + 1][m] = v.y;
            As[kk + 2][m] = v.z; As[kk + 3][m] = v.w;
        }
        {
            int n = tid >> 4;                 // 0..15
            int kk = (tid & 15) << 2;
            float4 v = *(const float4*)&Wa[(size_t)(n0 + n) * 1024 + k0 + kk];
            Ws[kk + 0][n] = v.x; Ws[kk + 1][n] = v.y;
            Ws[kk + 2][n] = v.z; Ws[kk + 3][n] = v.w;
        }
        __syncthreads();
        #pragma unroll
        for (int kk = 0; kk < 64; ++kk)
            acc += As[kk][tm] * Ws[kk][tn];
        __syncthreads();
    }
    float th = tanhf(acc);
    int m = m0 + tm, n = n0 + tn;
    Abuf[m * 512 + n] = th;
    Abufb[m * 512 + n] = f2bf(th);
}

// ---------------------------------------------------------------------------
// Logits GEMM via bf16 MFMA. CACHED=1: B from pre-converted bf16 cache;
// CACHED=0: fc_w fp32 converted on the fly (identical RNE rounding).
// Writes raw biased logits + per-chunk (max, sumexp); atomicMax row max.
// ---------------------------------------------------------------------------
template <int CACHED>
__global__ __launch_bounds__(256) void logits_mfma(
    const u16* __restrict__ Abufb, const float* __restrict__ fcw,
    const u16* __restrict__ fcwb, const float* __restrict__ fc_b,
    float* __restrict__ outp, float* __restrict__ pmax,
    float* __restrict__ psum, unsigned* __restrict__ rowmax)
{
    __shared__ u16 sA[64 * 512];     // 64KB, XOR-swizzled; reused after
    const int tid = threadIdx.x;
    const int wv = tid >> 6, lane = tid & 63;
    const int nb = blockIdx.x * 256;
    const int col16 = lane & 15, grp = lane >> 4;

    #pragma unroll
    for (int i = 0; i < 16; ++i) {
        int c = tid + i * 256;
        int m = c >> 6;
        int cb = (c & 63) << 4;
        int sb = cb ^ ((m & 7) << 4);
        *(u16x8*)((char*)sA + m * 1024 + sb) =
            *(const u16x8*)(Abufb + m * 512 + (cb >> 1));
    }
    __syncthreads();

    int nfb[4]; bool val[4];
    #pragma unroll
    for (int fn = 0; fn < 4; ++fn) {
        nfb[fn] = nb + wv * 64 + fn * 16;
        val[fn] = nfb[fn] < V_;
    }

    f32x4 acc[4][4];
    #pragma unroll
    for (int a = 0; a < 4; ++a)
        #pragma unroll
        for (int b2 = 0; b2 < 4; ++b2) acc[a][b2] = (f32x4){0.f, 0.f, 0.f, 0.f};

    if (CACHED) {
        const u16* wpb[4];
        #pragma unroll
        for (int fn = 0; fn < 4; ++fn) {
            size_t rowi = val[fn] ? (size_t)(nfb[fn] + col16) : 0;
            wpb[fn] = fcwb + rowi * 512 + (grp << 3);
        }
        bf16x8 bcur[4];
        #pragma unroll
        for (int fn = 0; fn < 4; ++fn) bcur[fn] = *(const bf16x8*)(wpb[fn]);
        for (int kt = 0; kt < 16; ++kt) {
            bf16x8 bnxt[4];
            int ktn = (kt < 15) ? kt + 1 : 15;
            #pragma unroll
            for (int fn = 0; fn < 4; ++fn)
                bnxt[fn] = *(const bf16x8*)(wpb[fn] + ktn * 32);
            bf16x8 af[4];
            int kb = kt * 64 + (grp << 4);
            #pragma unroll
            for (int fm = 0; fm < 4; ++fm) {
                int mg = fm * 16 + col16;
                af[fm] = *(const bf16x8*)((const char*)sA + mg * 1024 + (kb ^ ((mg & 7) << 4)));
            }
            #pragma unroll
            for (int fm = 0; fm < 4; ++fm)
                #pragma unroll
                for (int fn = 0; fn < 4; ++fn)
                    acc[fm][fn] = __builtin_amdgcn_mfma_f32_16x16x32_bf16(
                        af[fm], bcur[fn], acc[fm][fn], 0, 0, 0);
            #pragma unroll
            for (int fn = 0; fn < 4; ++fn) bcur[fn] = bnxt[fn];
        }
    } else {
        const float* wp[4];
        #pragma unroll
        for (int fn = 0; fn < 4; ++fn) {
            size_t rowi = val[fn] ? (size_t)(nfb[fn] + col16) : 0;
            wp[fn] = fcw + rowi * 512 + (grp << 3);
        }
        float4 lo[4], hi[4];
        #pragma unroll
        for (int fn = 0; fn < 4; ++fn) {
            lo[fn] = *(const float4*)(wp[fn]);
            hi[fn] = *(const float4*)(wp[fn] + 4);
        }
        for (int kt = 0; kt < 16; ++kt) {
            float4 nl[4], nh[4];
            int ktn = (kt < 15) ? kt + 1 : 15;
            #pragma unroll
            for (int fn = 0; fn < 4; ++fn) {
                nl[fn] = *(const float4*)(wp[fn] + ktn * 32);
                nh[fn] = *(const float4*)(wp[fn] + ktn * 32 + 4);
            }
            bf16x8 bc[4];
            #pragma unroll
            for (int fn = 0; fn < 4; ++fn) {
                union { unsigned u[4]; bf16x8 v; } cv;
                cv.u[0] = pk2(lo[fn].x, lo[fn].y);
                cv.u[1] = pk2(lo[fn].z, lo[fn].w);
                cv.u[2] = pk2(hi[fn].x, hi[fn].y);
                cv.u[3] = pk2(hi[fn].z, hi[fn].w);
                bc[fn] = cv.v;
            }
            bf16x8 af[4];
            int kb = kt * 64 + (grp << 4);
            #pragma unroll
            for (int fm = 0; fm < 4; ++fm) {
                int mg = fm * 16 + col16;
                af[fm] = *(const bf16x8*)((const char*)sA + mg * 1024 + (kb ^ ((mg & 7) << 4)));
            }
            #pragma unroll
            for (int fm = 0; fm < 4; ++fm)
                #pragma unroll
                for (int fn = 0; fn < 4; ++fn)
                    acc[fm][fn] = __builtin_amdgcn_mfma_f32_16x16x32_bf16(
                        af[fm], bc[fn], acc[fm][fn], 0, 0, 0);
            #pragma unroll
            for (int fn = 0; fn < 4; ++fn) { lo[fn] = nl[fn]; hi[fn] = nh[fn]; }
        }
    }
    __syncthreads();   // A reads done; reuse sA

    float* wmaxp = (float*)sA;            // [4][64]
    float* wsump = (float*)(sA + 512);

    float bias[4];
    #pragma unroll
    for (int fn = 0; fn < 4; ++fn) bias[fn] = val[fn] ? fc_b[nfb[fn] + col16] : 0.f;

    #pragma unroll
    for (int fm = 0; fm < 4; ++fm) {
        #pragma unroll
        for (int r = 0; r < 4; ++r) {
            int mrow = fm * 16 + grp * 4 + r;
            float best = -INFINITY;
            float vv[4];
            #pragma unroll
            for (int fn = 0; fn < 4; ++fn) {
                float v = -INFINITY;
                if (val[fn]) {
                    v = acc[fm][fn][r] + bias[fn];
                    outp[(size_t)mrow * LDCV + nfb[fn] + col16] = v;
                    best = fmaxf(best, v);
                }
                vv[fn] = v;
            }
            #pragma unroll
            for (int d = 1; d < 16; d <<= 1) best = fmaxf(best, __shfl_xor(best, d));
            float s = 0.f;
            #pragma unroll
            for (int fn = 0; fn < 4; ++fn)
                if (val[fn]) s += __expf(vv[fn] - best);
            #pragma unroll
            for (int d = 1; d < 16; d <<= 1) s += __shfl_xor(s, d);
            if (col16 == 0) {
                wmaxp[wv * 64 + mrow] = best;
                wsump[wv * 64 + mrow] = s;
            }
        }
    }
    __syncthreads();
    if (tid < 64) {
        float gm = -INFINITY;
        #pragma unroll
        for (int w = 0; w < 4; ++w) gm = fmaxf(gm, wmaxp[w * 64 + tid]);
        float gs = 0.f;
        #pragma unroll
        for (int w = 0; w < 4; ++w)
            gs += wsump[w * 64 + tid] * __expf(wmaxp[w * 64 + tid] - gm);
        pmax[tid * NCHUNK + blockIdx.x] = gm;
        psum[tid * NCHUNK + blockIdx.x] = gs;
        atomicMax(rowmax + tid, fenc(gm));
    }
}

// ---------------------------------------------------------------------------
// candrefine: grid (NCHUNK, B_). Chunk-0 blocks compute logZ. Blocks whose
// chunk max is within MARGIN of the row max recompute qualifying columns in
// exact fp32, block-reduce to ONE (value,idx) pack, and publish with a
// SINGLE atomicMax per block.
// ---------------------------------------------------------------------------
__global__ __launch_bounds__(256) void candrefine(
    const float* __restrict__ pmax, const float* __restrict__ psum,
    const float* __restrict__ out, const float* __restrict__ Abuf,
    const float* __restrict__ fcw, const float* __restrict__ fc_b,
    const unsigned* __restrict__ rowmax, u64* __restrict__ win64,
    float* __restrict__ logZ_arr, int t)
{
    const int c = blockIdx.x, b = blockIdx.y, tid = threadIdx.x;
    __shared__ float sv[256];

    float Mb = fdec(rowmax[b]);

    if (c == 0) {   // logZ for row b from chunk partials
        float pm_ = (tid < NCHUNK) ? pmax[b * NCHUNK + tid] : -INFINITY;
        sv[tid] = (tid < NCHUNK) ? psum[b * NCHUNK + tid] * __expf(pm_ - Mb) : 0.f;
        __syncthreads();
        for (int st = 128; st; st >>= 1) {
            if (tid < st) sv[tid] += sv[tid + st];
            __syncthreads();
        }
        if (tid == 0) logZ_arr[b * T_ + t] = Mb + logf(sv[0]);
        __syncthreads();
    }

    if (pmax[b * NCHUNK + c] < Mb - MARGIN) return;   // block-uniform

    __shared__ float A[512];
    __shared__ u64 sp[256];
    A[tid] = Abuf[b * 512 + tid];
    A[tid + 256] = Abuf[b * 512 + 256 + tid];
    __syncthreads();

    u64 pk = 0ull;
    int n = c * 256 + tid;
    if (n < V_) {
        float L = out[(size_t)b * LDCV + (size_t)t * V_ + n];
        if (L >= Mb - MARGIN) {
            const float* wr = fcw + (size_t)n * 512;
            float d = fc_b[n];
            #pragma unroll 8
            for (int k = 0; k < 512; k += 4) {
                float4 w4 = *(const float4*)&wr[k];
                d += A[k] * w4.x + A[k + 1] * w4.y + A[k + 2] * w4.z + A[k + 3] * w4.w;
            }
            pk = ((u64)fenc(d) << 32) | (u64)(~(unsigned)n);
        }
    }
    sp[tid] = pk;
    __syncthreads();
    for (int st = 128; st; st >>= 1) {
        if (tid < st) { u64 o = sp[tid + st]; if (o > sp[tid]) sp[tid] = o; }
        __syncthreads();
    }
    if (tid == 0 && sp[0] != 0ull) atomicMax(&win64[b], sp[0]);
}

// out[row][:] -= logZ[row]; one block per row (2048), grid-stride cols.
__global__ __launch_bounds__(256) void norm_all(
    float* __restrict__ out, const float* __restrict__ logZ_arr)
{
    int row = blockIdx.x;
    float z = logZ_arr[row];
    float4* base = (float4*)(out + (size_t)row * V_);
    for (int j = threadIdx.x; j < 12500; j += 256) {
        float4 v = base[j];
        v.x -= z; v.y -= z; v.z -= z; v.w -= z;
        base[j] = v;
    }
}

__global__ __launch_bounds__(256) void final_copy(
    const float* __restrict__ hfin, float* __restrict__ dst)
{
    int idx = blockIdx.x * 256 + threadIdx.x;
    if (idx < B_ * H_) dst[idx] = hfin[idx];
}

// ---------------------------------------------------------------------------
extern "C" void kernel_launch(void* const* d_in, const int* in_sizes, int n_in,
                              void* d_out, int out_size, void* d_ws, size_t ws_size,
                              hipStream_t stream)
{
    const float* enc_hidden = (const float*)d_in[0];
    const float* enc    = (const float*)d_in[3];
    const float* emb    = (const float*)d_in[4];
    const float* w_ih   = (const float*)d_in[5];
    const float* w_hh   = (const float*)d_in[6];
    const float* b_ih   = (const float*)d_in[7];
    const float* b_hh   = (const float*)d_in[8];
    const float* attn_w = (const float*)d_in[9];
    const float* Wa     = (const float*)d_in[10];
    const float* fc_w   = (const float*)d_in[11];
    const float* fc_b   = (const float*)d_in[12];
    float* out = (float*)d_out;
    float* ws  = (float*)d_ws;

    // ws layout (float units) — base ≈ 8.2 MB (+51.2 MB bf16 cache if it fits)
    size_t off = 0;
    float* WbigT   = ws + off; off += 1572864;
    float* biasBig = ws + off; off += 2048;
    float* awT     = ws + off; off += 262144;
    float* hbuf0   = ws + off; off += 32768;
    float* hbuf1   = ws + off; off += 32768;
    float* concatA = ws + off; off += 65536;
    float* Abuf    = ws + off; off += 32768;
    u16*   Abufb   = (u16*)(ws + off); off += 16384;
    float* pmax    = ws + off; off += 64 * NCHUNK;
    float* psum    = ws + off; off += 64 * NCHUNK;
    float* logZ_a  = ws + off; off += 64 * T_;
    unsigned* rowmax = (unsigned*)(ws + off); off += 64;
    off = (off + 1) & ~(size_t)1;                    // 8B-align win64
    u64*   win64   = (u64*)(ws + off); off += 128;
    off = (off + 3) & ~(size_t)3;                    // 16B-align the bf16 cache
    u16*   fcwb    = (u16*)(ws + off);
    const bool big = ws_size >= (off + 12800000) * 4;   // + 50000*512 bf16

    build_wbig<<<1536, 256, 0, stream>>>(w_ih, w_hh, b_ih, b_hh, WbigT, biasBig);
    transpose_aw<<<1024, 256, 0, stream>>>(attn_w, awT);
    init_state<<<128, 256, 0, stream>>>(enc_hidden, hbuf0, win64, rowmax);
    if (big) conv_fcw<<<2048, 256, 0, stream>>>(fc_w, fcwb);

    for (int t = 0; t < T_; ++t) {
        float* hcur = (t & 1) ? hbuf1 : hbuf0;
        float* hnxt = (t & 1) ? hbuf0 : hbuf1;
        float* outp = out + (size_t)t * V_;

        gruh<<<128, 256, 0, stream>>>(WbigT, biasBig, emb, win64, hcur, hnxt, concatA);
        attnq<<<64, 256, 0, stream>>>(hnxt, awT, enc, concatA);
        ctxtanh<<<128, 256, 0, stream>>>(concatA, Wa, Abuf, Abufb, win64, rowmax);
        if (big)
            logits_mfma<1><<<NCHUNK, 256, 0, stream>>>(
                Abufb, fc_w, fcwb, fc_b, outp, pmax, psum, rowmax);
        else
            logits_mfma<0><<<NCHUNK, 256, 0, stream>>>(
                Abufb, fc_w, fcwb, fc_b, outp, pmax, psum, rowmax);
        candrefine<<<dim3(NCHUNK, B_), 256, 0, stream>>>(
            pmax, psum, out, Abuf, fc_w, fc_b, rowmax, win64, logZ_a, t);
    }

    norm_all<<<2048, 256, 0, stream>>>(out, logZ_a);
    final_copy<<<128, 256, 0, stream>>>(hbuf0, out + (size_t)B_ * T_ * V_);
}